// Round 24
// baseline (60.034 us; speedup 1.0000x reference)
//
#include <hip/hip_runtime.h>
#include <hip/hip_bf16.h>
#include <hip/hip_fp8.h>
#include <stdint.h>

#define NROW 8192
#define DIM  512
#define BM   128
#define BN   128
#define BKB  128                  // K-step in BYTES (=128 fp8 elements)
#define NTK  (DIM / BKB)          // 4 K-steps
#define NT   (NROW / BM)          // 64 tile rows/cols
#define NBLK (NT * (NT + 1) / 2)  // 2080 upper-triangular tiles (= 8 * 260)
#define RST  20                   // row stride (floats) in epilogue LDS acc

typedef float f32x4 __attribute__((ext_vector_type(4)));
typedef int   i32x4 __attribute__((ext_vector_type(4)));
typedef int   i32x8 __attribute__((ext_vector_type(8)));

__device__ __forceinline__ float fast_sqrtf(float x) {
    return __builtin_amdgcn_sqrtf(x);   // raw v_sqrt_f32; tolerance is 1.5e-2
}

__device__ __forceinline__ unsigned char f32_to_e4m3(float f) {
    __hip_fp8_e4m3 q(f);                // OCP e4m3fn, RNE + satfinite
    return (unsigned char)q.__x;
}

// ---------------------------------------------------------------------------
// prep: blocks 0..2047: z (fp32) -> zq (fp8 e4m3), sq[i] = ||z_i||^2 (fp32).
// block 2048: hist via LDS atomics + zero init of totals/done_ctr.
// ---------------------------------------------------------------------------
__global__ __launch_bounds__(256) void prep_kernel(
    const float* __restrict__ z, const int* __restrict__ labels,
    unsigned char* __restrict__ zq, float* __restrict__ sq,
    int* __restrict__ hist, float* __restrict__ totals,
    int* __restrict__ done_ctr)
{
    if (blockIdx.x == NROW / 4) {
        __shared__ int lh[64];
        const int tid = threadIdx.x;
        if (tid < 64) lh[tid] = 0;
        __syncthreads();
        for (int i = tid; i < NROW; i += 256)
            atomicAdd(&lh[labels[i]], 1);    // LDS atomics: no XCD ping-pong
        __syncthreads();
        if (tid < 64) hist[tid] = lh[tid];
        if (tid == 64) { totals[0] = 0.f; totals[1] = 0.f; }
        if (tid == 65) { *done_ctr = 0; }
        return;
    }

    const int lane = threadIdx.x & 63;
    const int wave = threadIdx.x >> 6;
    const int row  = blockIdx.x * 4 + wave;

    const float4* zr = (const float4*)(z + (size_t)row * DIM);
    float4 v0 = zr[lane * 2 + 0];
    float4 v1 = zr[lane * 2 + 1];
    float s = v0.x*v0.x + v0.y*v0.y + v0.z*v0.z + v0.w*v0.w
            + v1.x*v1.x + v1.y*v1.y + v1.z*v1.z + v1.w*v1.w;

    union { unsigned char b[8]; int2 v; } pk;
    pk.b[0] = f32_to_e4m3(v0.x); pk.b[1] = f32_to_e4m3(v0.y);
    pk.b[2] = f32_to_e4m3(v0.z); pk.b[3] = f32_to_e4m3(v0.w);
    pk.b[4] = f32_to_e4m3(v1.x); pk.b[5] = f32_to_e4m3(v1.y);
    pk.b[6] = f32_to_e4m3(v1.z); pk.b[7] = f32_to_e4m3(v1.w);
    ((int2*)(zq + (size_t)row * DIM))[lane] = pk.v;

    #pragma unroll
    for (int sft = 1; sft < 64; sft <<= 1) s += __shfl_xor(s, sft);
    if (lane == 0) sq[row] = s;
}

// ---------------------------------------------------------------------------
// tile: 128x128 Gram tile (upper triangle), MX 16x16x128 fp8 MFMA (scale=1).
// K-loop = R18 verbatim. Epilogue = R23 (LDS-accumulate, predicated diag,
// neg = tot - pos; verified -10 µs).
// R24 change: sq/labels STAGED INTO LDS once per block (2 coalesced loads/
// thread, hidden under the K-loop; region [43008,45056) — disjoint from
// As/Bs and the epilogue overlay). Epilogue tail then has ZERO scattered
// VMEM loads (was ~40/lane of 4-lane-broadcast L2 reads — R22's abl_epi
// FETCH blowup fingered exactly these).
// LDS 45056 B -> still 3 blocks/CU (135 KB/CU). acc inline (rule #20);
// unique-writer stores (no atomics).
// ---------------------------------------------------------------------------
__global__ __launch_bounds__(256, 3) void tile_kernel(
    const unsigned char* __restrict__ zq,
    const float* __restrict__ sq, const int* __restrict__ labels,
    float* __restrict__ partial_pos, float* __restrict__ partial_neg)
{
    __shared__ __align__(16) float smem_f[11264];   // 45056 B
    unsigned char* As = (unsigned char*)smem_f;            // [0, 16384)
    unsigned char* Bs = (unsigned char*)smem_f + 16384;    // [16384, 32768)
    // preload region (disjoint from K-loop bufs AND epilogue overlay):
    float* rsqL = smem_f + 10752;              // 128 f32: sq[row0..+128)
    float* csqL = smem_f + 10880;              // 128 f32: sq[col0..+128)
    int*   rlbL = (int*)(smem_f + 11008);      // 128 i32: labels[row0..)
    int*   clbL = (int*)(smem_f + 11136);      // 128 i32: labels[col0..)

    const int tid  = threadIdx.x;
    const int lane = tid & 63;
    const int wave = tid >> 6;
    const int wm = wave >> 1;
    const int wn = wave & 1;

    // XCD-chunked bijective remap (2080 = 8*260), then triangular decode
    const int bid  = (int)blockIdx.x;
    int bidx = (bid & 7) * (NBLK / 8) + (bid >> 3);
    int tm = 0, rem = bidx;
    while (rem >= NT - tm) { rem -= NT - tm; ++tm; }
    const int tn = tm + rem;
    const int row0 = tm * BM;
    const int col0 = tn * BN;
    const bool offdiag = (tm != tn);

    // stage sq/labels (coalesced; visible after the first K-loop barrier)
    {
        const int  i     = tid & 127;
        const bool isCol = tid >= 128;
        const int  g     = (isCol ? col0 : row0) + i;
        (isCol ? csqL : rsqL)[i] = sq[g];
        (isCol ? clbL : rlbL)[i] = labels[g];
    }

    f32x4 acc[4][4];
    #pragma unroll
    for (int m = 0; m < 4; ++m)
        #pragma unroll
        for (int n = 0; n < 4; ++n)
            acc[m][n] = (f32x4){0.f, 0.f, 0.f, 0.f};

    const int srow   = tid >> 3;
    const int sinner = (tid & 7) << 4;
    const int kbsw   = sinner ^ ((srow & 7) << 4);
    const unsigned char* baseA = zq + (size_t)(row0 + srow) * DIM + kbsw;
    const unsigned char* baseB = zq + (size_t)(col0 + srow) * DIM + kbsw;

    const int swz  = (lane & 7) << 4;
    const int hi32 = (lane >> 4) << 5;
    const unsigned char* apc0 = As + (wm * 64 + (lane & 15)) * BKB + ((hi32 +  0) ^ swz);
    const unsigned char* apc1 = As + (wm * 64 + (lane & 15)) * BKB + ((hi32 + 16) ^ swz);
    const unsigned char* bpc0 = Bs + (wn * 64 + (lane & 15)) * BKB + ((hi32 +  0) ^ swz);
    const unsigned char* bpc1 = Bs + (wn * 64 + (lane & 15)) * BKB + ((hi32 + 16) ^ swz);

#define FRAG(pc0, pc1, off)                                                    \
    __builtin_shufflevector(*(const i32x4*)((pc0) + (off)),                    \
                            *(const i32x4*)((pc1) + (off)), 0, 1, 2, 3, 4, 5, 6, 7)
#define MFMA128(a, b, c)                                                       \
    __builtin_amdgcn_mfma_scale_f32_16x16x128_f8f6f4(                          \
        (a), (b), (c), 0, 0, 0, 0x7F7F7F7F, 0, 0x7F7F7F7F)

    #pragma unroll 1
    for (int t = 0; t < NTK; ++t) {
        const int k0 = t * BKB;
        #pragma unroll
        for (int r = 0; r < 4; ++r) {
            __builtin_amdgcn_global_load_lds(
                (const __attribute__((address_space(1))) void*)(baseA + (size_t)r * 32 * DIM + k0),
                (__attribute__((address_space(3))) void*)(As + r * 4096 + tid * 16),
                16, 0, 0);
            __builtin_amdgcn_global_load_lds(
                (const __attribute__((address_space(1))) void*)(baseB + (size_t)r * 32 * DIM + k0),
                (__attribute__((address_space(3))) void*)(Bs + r * 4096 + tid * 16),
                16, 0, 0);
        }
        __syncthreads();
        i32x8 bg0 = FRAG(bpc0, bpc1, 0 * 2048);
        i32x8 bg1 = FRAG(bpc0, bpc1, 1 * 2048);
        i32x8 bg2 = FRAG(bpc0, bpc1, 2 * 2048);
        i32x8 bg3 = FRAG(bpc0, bpc1, 3 * 2048);
        #pragma unroll
        for (int m = 0; m < 4; ++m) {
            i32x8 af = FRAG(apc0, apc1, m * 2048);
            acc[m][0] = MFMA128(af, bg0, acc[m][0]);
            acc[m][1] = MFMA128(af, bg1, acc[m][1]);
            acc[m][2] = MFMA128(af, bg2, acc[m][2]);
            acc[m][3] = MFMA128(af, bg3, acc[m][3]);
        }
        __syncthreads();   // last iter: all As/Bs reads done -> overlay safe
    }
#undef FRAG
#undef MFMA128

    // ---- epilogue (inline — R15 lesson); all operands from LDS ----
    // C/D map: col = lane&15, row = (lane>>4)*4 + r  (m89-verified)
    const int lo = lane & 15;
    const int hi = lane >> 4;

    float csq[4]; int clb[4];
    #pragma unroll
    for (int n = 0; n < 4; ++n) {
        int cl = wn * 64 + n * 16 + lo;
        csq[n] = csqL[cl];
        clb[n] = clbL[cl];
    }

    // diagonal predicates: cg==rg <=> wm==wn && n==m && lo==hi*4+r
    const bool dwv = (!offdiag) && (wm == wn);
    bool dpred[4];
    #pragma unroll
    for (int r = 0; r < 4; ++r)
        dpred[r] = dwv && (lo == hi * 4 + r);

    float cpos[4] = {0.f, 0.f, 0.f, 0.f};
    float ctot[4] = {0.f, 0.f, 0.f, 0.f};

    // rowacc: pos at [0, 5120) f32, tot at [5120, 10240); colacc at 10240+.
    float* posrow = smem_f + (wn * 128 + wm * 64 + hi * 4) * RST + lo;
    float* cpb    = smem_f + 10240;
    float* cnb    = cpb + 256;

    #pragma unroll
    for (int m = 0; m < 4; ++m) {
        #pragma unroll
        for (int r = 0; r < 4; ++r) {
            const int rowl = wm * 64 + m * 16 + hi * 4 + r;
            const float rs = rsqL[rowl];
            const int   rl = rlbL[rowl];
            float pos = 0.f, tot = 0.f;
            #pragma unroll
            for (int n = 0; n < 4; ++n) {
                float d2   = rs + csq[n] - 2.0f * acc[m][n][r];
                float dist = d2 > 0.f ? fast_sqrtf(d2) : 0.f;
                if (n == m) dist = dpred[r] ? 0.f : dist;   // exact diag zero
                float dp = (rl == clb[n]) ? dist : 0.f;
                pos += dp;  tot += dist;
                cpos[n] += dp;  ctot[n] += dist;
            }
            posrow[(m * 16 + r) * RST]        = pos;   // unique-writer slots
            posrow[(m * 16 + r) * RST + 5120] = tot;
        }
    }

    // column sums: only 16 shuffles total
    #pragma unroll
    for (int n = 0; n < 4; ++n) {
        cpos[n] += __shfl_xor(cpos[n], 16);
        cpos[n] += __shfl_xor(cpos[n], 32);
        ctot[n] += __shfl_xor(ctot[n], 16);
        ctot[n] += __shfl_xor(ctot[n], 32);
        if (lane < 16) {
            int coll = wn * 64 + n * 16 + lane;
            cpb[wm * 128 + coll] = cpos[n];
            cnb[wm * 128 + coll] = ctot[n];
        }
    }
    __syncthreads();

    // merge pass: row = tid (<128); sum 2 wn-buffers x 16 slots, b128 reads
    if (tid < 128) {
        float ps = 0.f, ts = 0.f;
        #pragma unroll
        for (int w = 0; w < 2; ++w) {
            const float* pr = smem_f + (w * 128 + tid) * RST;
            #pragma unroll
            for (int j = 0; j < 16; j += 4) {
                f32x4 a = *(const f32x4*)(pr + j);
                f32x4 b = *(const f32x4*)(pr + 5120 + j);
                ps += a[0] + a[1] + a[2] + a[3];
                ts += b[0] + b[1] + b[2] + b[3];
            }
        }
        partial_pos[(size_t)tn * NROW + row0 + tid] = ps;
        partial_neg[(size_t)tn * NROW + row0 + tid] = ts - ps;
        if (offdiag) {
            float p2 = cpb[tid] + cpb[128 + tid];
            float t2 = cnb[tid] + cnb[128 + tid];
            partial_pos[(size_t)tm * NROW + col0 + tid] = p2;
            partial_neg[(size_t)tm * NROW + col0 + tid] = t2 - p2;
        }
    }
}

// ---------------------------------------------------------------------------
// row loss: sum the 64 per-slot partials, margin/relu/reduce; the LAST block
// (device-scope counter) computes the final quotient.
// ---------------------------------------------------------------------------
__global__ __launch_bounds__(256) void rowloss_kernel(
    const float* __restrict__ partial_pos, const float* __restrict__ partial_neg,
    const int* __restrict__ labels, const int* __restrict__ hist,
    float* __restrict__ totals, int* __restrict__ done_ctr,
    float* __restrict__ out)
{
    const int i = blockIdx.x * 256 + threadIdx.x;
    float ps = 0.f, ns = 0.f;
    #pragma unroll 8
    for (int s = 0; s < NT; ++s) {
        ps += partial_pos[(size_t)s * NROW + i];
        ns += partial_neg[(size_t)s * NROW + i];
    }
    const float pc = (float)hist[labels[i]];        // includes self
    const float nc = (float)NROW - pc;
    const float pm = ps / fmaxf(pc, 1.f);
    const float nm = ns / fmaxf(nc, 1.f);
    const bool valid = (pc > 1.f) && (nc > 0.f);
    float t = valid ? fmaxf(pm - nm + 1.0f, 0.f) : 0.f;
    float c = valid ? 1.f : 0.f;
    #pragma unroll
    for (int s = 1; s < 64; s <<= 1) {
        t += __shfl_xor(t, s);
        c += __shfl_xor(c, s);
    }
    __shared__ float blk[8];
    const int wv = threadIdx.x >> 6;
    if ((threadIdx.x & 63) == 0) { blk[wv] = t; blk[4 + wv] = c; }
    __syncthreads();
    if (threadIdx.x == 0) {
        atomicAdd(&totals[0], blk[0] + blk[1] + blk[2] + blk[3]);
        atomicAdd(&totals[1], blk[4] + blk[5] + blk[6] + blk[7]);
        __threadfence();
        int prev = atomicAdd(done_ctr, 1);
        if (prev == (int)gridDim.x - 1) {
            float tt = atomicAdd(&totals[0], 0.f);
            float cc = atomicAdd(&totals[1], 0.f);
            out[0] = tt / fmaxf(cc, 1.f);
        }
    }
}

// ---------------------------------------------------------------------------
extern "C" void kernel_launch(void* const* d_in, const int* in_sizes, int n_in,
                              void* d_out, int out_size, void* d_ws, size_t ws_size,
                              hipStream_t stream) {
    (void)in_sizes; (void)n_in; (void)out_size; (void)ws_size;
    const float* z      = (const float*)d_in[0];
    const int*   labels = (const int*)d_in[1];
    float*       out    = (float*)d_out;

    char* ws = (char*)d_ws;
    float* partial_pos = (float*)(ws);                      // 2 MiB (64 x 8192 f32)
    float* partial_neg = (float*)(ws + 2097152);            // 2 MiB
    int*   hist     = (int*)  (ws + 4194304);               // 256 B
    float* totals   = (float*)(ws + 4194560);               // 8 B
    int*   done_ctr = (int*)  (ws + 4194568);               // 4 B
    unsigned char* zq = (unsigned char*)(ws + 4194816);     // 4 MiB (fp8)
    float* sq       = (float*)(ws + 4194816 + (size_t)NROW * DIM); // 32 KiB

    // no memset: prep's extra block zeroes hist/totals/done_ctr;
    // partials are written exactly once per launch.
    prep_kernel    <<<NROW / 4 + 1, 256, 0, stream>>>(z, labels, zq, sq, hist,
                                                      totals, done_ctr);
    tile_kernel    <<<NBLK, 256, 0, stream>>>(zq, sq, labels, partial_pos, partial_neg);
    rowloss_kernel <<<NROW / 256, 256, 0, stream>>>(partial_pos, partial_neg, labels,
                                                    hist, totals, done_ctr, out);
}

// Round 25
// 55.193 us; speedup vs baseline: 1.0877x; 1.0877x over previous
//
#include <hip/hip_runtime.h>
#include <hip/hip_bf16.h>
#include <hip/hip_fp8.h>
#include <stdint.h>

#define NROW 8192
#define DIM  512
#define BM   128
#define BN   128
#define BKB  128                  // K-step in BYTES (=128 fp8 elements)
#define NTK  (DIM / BKB)          // 4 K-steps
#define NT   (NROW / BM)          // 64 tile rows/cols
#define NBLK (NT * (NT + 1) / 2)  // 2080 upper-triangular tiles (= 8 * 260)
#define RST  20                   // row stride (floats) in epilogue LDS acc

typedef float f32x4 __attribute__((ext_vector_type(4)));
typedef int   i32x4 __attribute__((ext_vector_type(4)));
typedef int   i32x8 __attribute__((ext_vector_type(8)));

__device__ __forceinline__ float fast_sqrtf(float x) {
    return __builtin_amdgcn_sqrtf(x);   // raw v_sqrt_f32; tolerance is 1.5e-2
}

__device__ __forceinline__ unsigned char f32_to_e4m3(float f) {
    __hip_fp8_e4m3 q(f);                // OCP e4m3fn, RNE + satfinite
    return (unsigned char)q.__x;
}

// ---------------------------------------------------------------------------
// prep: blocks 0..2047: z (fp32) -> zq (fp8 e4m3), sq[i] = ||z_i||^2 (fp32).
// block 2048: hist via LDS atomics + zero init of totals/done_ctr.
// ---------------------------------------------------------------------------
__global__ __launch_bounds__(256) void prep_kernel(
    const float* __restrict__ z, const int* __restrict__ labels,
    unsigned char* __restrict__ zq, float* __restrict__ sq,
    int* __restrict__ hist, float* __restrict__ totals,
    int* __restrict__ done_ctr)
{
    if (blockIdx.x == NROW / 4) {
        __shared__ int lh[64];
        const int tid = threadIdx.x;
        if (tid < 64) lh[tid] = 0;
        __syncthreads();
        for (int i = tid; i < NROW; i += 256)
            atomicAdd(&lh[labels[i]], 1);    // LDS atomics: no XCD ping-pong
        __syncthreads();
        if (tid < 64) hist[tid] = lh[tid];
        if (tid == 64) { totals[0] = 0.f; totals[1] = 0.f; }
        if (tid == 65) { *done_ctr = 0; }
        return;
    }

    const int lane = threadIdx.x & 63;
    const int wave = threadIdx.x >> 6;
    const int row  = blockIdx.x * 4 + wave;

    const float4* zr = (const float4*)(z + (size_t)row * DIM);
    float4 v0 = zr[lane * 2 + 0];
    float4 v1 = zr[lane * 2 + 1];
    float s = v0.x*v0.x + v0.y*v0.y + v0.z*v0.z + v0.w*v0.w
            + v1.x*v1.x + v1.y*v1.y + v1.z*v1.z + v1.w*v1.w;

    union { unsigned char b[8]; int2 v; } pk;
    pk.b[0] = f32_to_e4m3(v0.x); pk.b[1] = f32_to_e4m3(v0.y);
    pk.b[2] = f32_to_e4m3(v0.z); pk.b[3] = f32_to_e4m3(v0.w);
    pk.b[4] = f32_to_e4m3(v1.x); pk.b[5] = f32_to_e4m3(v1.y);
    pk.b[6] = f32_to_e4m3(v1.z); pk.b[7] = f32_to_e4m3(v1.w);
    ((int2*)(zq + (size_t)row * DIM))[lane] = pk.v;

    #pragma unroll
    for (int sft = 1; sft < 64; sft <<= 1) s += __shfl_xor(s, sft);
    if (lane == 0) sq[row] = s;
}

// ---------------------------------------------------------------------------
// tile: 128x128 Gram tile (upper triangle), MX 16x16x128 fp8 MFMA (scale=1).
// R25 = R23 VERBATIM (best verified: 55.7 µs total). R24's sq/labels LDS
// preload regressed (+4.4 µs: extra VMEM serial with first STAGE; the
// scattered epilogue loads were already hidden) — reverted.
// K-loop = R18 structure (MX K=128, per-lane-const frag bases, immediate
// offsets). Epilogue = R23 (LDS-accumulate instead of 128 shuffles,
// predicated diag, neg = tot - pos).
// LDS 43008 B -> 3 blocks/CU. acc inline (rule #20); unique-writer stores.
// ---------------------------------------------------------------------------
__global__ __launch_bounds__(256, 3) void tile_kernel(
    const unsigned char* __restrict__ zq,
    const float* __restrict__ sq, const int* __restrict__ labels,
    float* __restrict__ partial_pos, float* __restrict__ partial_neg)
{
    __shared__ __align__(16) float smem_f[10752];   // 43008 B
    unsigned char* As = (unsigned char*)smem_f;            // 16 KiB
    unsigned char* Bs = (unsigned char*)smem_f + 16384;    // 16 KiB

    const int tid  = threadIdx.x;
    const int lane = tid & 63;
    const int wave = tid >> 6;
    const int wm = wave >> 1;
    const int wn = wave & 1;

    // XCD-chunked bijective remap (2080 = 8*260), then triangular decode
    const int bid  = (int)blockIdx.x;
    int bidx = (bid & 7) * (NBLK / 8) + (bid >> 3);
    int tm = 0, rem = bidx;
    while (rem >= NT - tm) { rem -= NT - tm; ++tm; }
    const int tn = tm + rem;
    const int row0 = tm * BM;
    const int col0 = tn * BN;
    const bool offdiag = (tm != tn);

    f32x4 acc[4][4];
    #pragma unroll
    for (int m = 0; m < 4; ++m)
        #pragma unroll
        for (int n = 0; n < 4; ++n)
            acc[m][n] = (f32x4){0.f, 0.f, 0.f, 0.f};

    const int srow   = tid >> 3;
    const int sinner = (tid & 7) << 4;
    const int kbsw   = sinner ^ ((srow & 7) << 4);
    const unsigned char* baseA = zq + (size_t)(row0 + srow) * DIM + kbsw;
    const unsigned char* baseB = zq + (size_t)(col0 + srow) * DIM + kbsw;

    const int swz  = (lane & 7) << 4;
    const int hi32 = (lane >> 4) << 5;
    const unsigned char* apc0 = As + (wm * 64 + (lane & 15)) * BKB + ((hi32 +  0) ^ swz);
    const unsigned char* apc1 = As + (wm * 64 + (lane & 15)) * BKB + ((hi32 + 16) ^ swz);
    const unsigned char* bpc0 = Bs + (wn * 64 + (lane & 15)) * BKB + ((hi32 +  0) ^ swz);
    const unsigned char* bpc1 = Bs + (wn * 64 + (lane & 15)) * BKB + ((hi32 + 16) ^ swz);

#define FRAG(pc0, pc1, off)                                                    \
    __builtin_shufflevector(*(const i32x4*)((pc0) + (off)),                    \
                            *(const i32x4*)((pc1) + (off)), 0, 1, 2, 3, 4, 5, 6, 7)
#define MFMA128(a, b, c)                                                       \
    __builtin_amdgcn_mfma_scale_f32_16x16x128_f8f6f4(                          \
        (a), (b), (c), 0, 0, 0, 0x7F7F7F7F, 0, 0x7F7F7F7F)

    #pragma unroll 1
    for (int t = 0; t < NTK; ++t) {
        const int k0 = t * BKB;
        #pragma unroll
        for (int r = 0; r < 4; ++r) {
            __builtin_amdgcn_global_load_lds(
                (const __attribute__((address_space(1))) void*)(baseA + (size_t)r * 32 * DIM + k0),
                (__attribute__((address_space(3))) void*)(As + r * 4096 + tid * 16),
                16, 0, 0);
            __builtin_amdgcn_global_load_lds(
                (const __attribute__((address_space(1))) void*)(baseB + (size_t)r * 32 * DIM + k0),
                (__attribute__((address_space(3))) void*)(Bs + r * 4096 + tid * 16),
                16, 0, 0);
        }
        __syncthreads();
        i32x8 bg0 = FRAG(bpc0, bpc1, 0 * 2048);
        i32x8 bg1 = FRAG(bpc0, bpc1, 1 * 2048);
        i32x8 bg2 = FRAG(bpc0, bpc1, 2 * 2048);
        i32x8 bg3 = FRAG(bpc0, bpc1, 3 * 2048);
        #pragma unroll
        for (int m = 0; m < 4; ++m) {
            i32x8 af = FRAG(apc0, apc1, m * 2048);
            acc[m][0] = MFMA128(af, bg0, acc[m][0]);
            acc[m][1] = MFMA128(af, bg1, acc[m][1]);
            acc[m][2] = MFMA128(af, bg2, acc[m][2]);
            acc[m][3] = MFMA128(af, bg3, acc[m][3]);
        }
        __syncthreads();   // last iter: all As/Bs reads done -> overlay safe
    }
#undef FRAG
#undef MFMA128

    // ---- R23 epilogue (inline — R15 lesson) ----
    // C/D map: col = lane&15, row = (lane>>4)*4 + r  (m89-verified)
    const int lo = lane & 15;
    const int hi = lane >> 4;
    const int colbase = col0 + wn * 64;

    float csq[4]; int clb[4];
    #pragma unroll
    for (int n = 0; n < 4; ++n) {
        int cg = colbase + n * 16 + lo;
        csq[n] = sq[cg];
        clb[n] = labels[cg];
    }

    // diagonal predicates: cg==rg <=> wm==wn && n==m && lo==hi*4+r
    const bool dwv = (!offdiag) && (wm == wn);
    bool dpred[4];
    #pragma unroll
    for (int r = 0; r < 4; ++r)
        dpred[r] = dwv && (lo == hi * 4 + r);

    float cpos[4] = {0.f, 0.f, 0.f, 0.f};
    float ctot[4] = {0.f, 0.f, 0.f, 0.f};

    // rowacc: pos at [0, 5120) f32, tot at [5120, 10240) f32, layout
    // [(wn*128 + rowl) * RST + lo]; colacc cp at 10240, cn at 10496.
    float* posrow = smem_f + (wn * 128 + wm * 64 + hi * 4) * RST + lo;
    float* cpb    = smem_f + 10240;
    float* cnb    = cpb + 256;

    #pragma unroll
    for (int m = 0; m < 4; ++m) {
        #pragma unroll
        for (int r = 0; r < 4; ++r) {
            const int rg = row0 + wm * 64 + m * 16 + hi * 4 + r;
            const float rs = sq[rg];
            const int   rl = labels[rg];
            float pos = 0.f, tot = 0.f;
            #pragma unroll
            for (int n = 0; n < 4; ++n) {
                float d2   = rs + csq[n] - 2.0f * acc[m][n][r];
                float dist = d2 > 0.f ? fast_sqrtf(d2) : 0.f;
                if (n == m) dist = dpred[r] ? 0.f : dist;   // exact diag zero
                float dp = (rl == clb[n]) ? dist : 0.f;
                pos += dp;  tot += dist;
                cpos[n] += dp;  ctot[n] += dist;
            }
            posrow[(m * 16 + r) * RST]        = pos;   // unique-writer slots
            posrow[(m * 16 + r) * RST + 5120] = tot;
        }
    }

    // column sums: only 16 shuffles total
    #pragma unroll
    for (int n = 0; n < 4; ++n) {
        cpos[n] += __shfl_xor(cpos[n], 16);
        cpos[n] += __shfl_xor(cpos[n], 32);
        ctot[n] += __shfl_xor(ctot[n], 16);
        ctot[n] += __shfl_xor(ctot[n], 32);
        if (lane < 16) {
            int coll = wn * 64 + n * 16 + lane;
            cpb[wm * 128 + coll] = cpos[n];
            cnb[wm * 128 + coll] = ctot[n];
        }
    }
    __syncthreads();

    // merge pass: row = tid (<128); sum 2 wn-buffers x 16 slots, b128 reads
    if (tid < 128) {
        float ps = 0.f, ts = 0.f;
        #pragma unroll
        for (int w = 0; w < 2; ++w) {
            const float* pr = smem_f + (w * 128 + tid) * RST;
            #pragma unroll
            for (int j = 0; j < 16; j += 4) {
                f32x4 a = *(const f32x4*)(pr + j);
                f32x4 b = *(const f32x4*)(pr + 5120 + j);
                ps += a[0] + a[1] + a[2] + a[3];
                ts += b[0] + b[1] + b[2] + b[3];
            }
        }
        partial_pos[(size_t)tn * NROW + row0 + tid] = ps;
        partial_neg[(size_t)tn * NROW + row0 + tid] = ts - ps;
        if (offdiag) {
            float p2 = cpb[tid] + cpb[128 + tid];
            float t2 = cnb[tid] + cnb[128 + tid];
            partial_pos[(size_t)tm * NROW + col0 + tid] = p2;
            partial_neg[(size_t)tm * NROW + col0 + tid] = t2 - p2;
        }
    }
}

// ---------------------------------------------------------------------------
// row loss: sum the 64 per-slot partials, margin/relu/reduce; the LAST block
// (device-scope counter) computes the final quotient.
// ---------------------------------------------------------------------------
__global__ __launch_bounds__(256) void rowloss_kernel(
    const float* __restrict__ partial_pos, const float* __restrict__ partial_neg,
    const int* __restrict__ labels, const int* __restrict__ hist,
    float* __restrict__ totals, int* __restrict__ done_ctr,
    float* __restrict__ out)
{
    const int i = blockIdx.x * 256 + threadIdx.x;
    float ps = 0.f, ns = 0.f;
    #pragma unroll 8
    for (int s = 0; s < NT; ++s) {
        ps += partial_pos[(size_t)s * NROW + i];
        ns += partial_neg[(size_t)s * NROW + i];
    }
    const float pc = (float)hist[labels[i]];        // includes self
    const float nc = (float)NROW - pc;
    const float pm = ps / fmaxf(pc, 1.f);
    const float nm = ns / fmaxf(nc, 1.f);
    const bool valid = (pc > 1.f) && (nc > 0.f);
    float t = valid ? fmaxf(pm - nm + 1.0f, 0.f) : 0.f;
    float c = valid ? 1.f : 0.f;
    #pragma unroll
    for (int s = 1; s < 64; s <<= 1) {
        t += __shfl_xor(t, s);
        c += __shfl_xor(c, s);
    }
    __shared__ float blk[8];
    const int wv = threadIdx.x >> 6;
    if ((threadIdx.x & 63) == 0) { blk[wv] = t; blk[4 + wv] = c; }
    __syncthreads();
    if (threadIdx.x == 0) {
        atomicAdd(&totals[0], blk[0] + blk[1] + blk[2] + blk[3]);
        atomicAdd(&totals[1], blk[4] + blk[5] + blk[6] + blk[7]);
        __threadfence();
        int prev = atomicAdd(done_ctr, 1);
        if (prev == (int)gridDim.x - 1) {
            float tt = atomicAdd(&totals[0], 0.f);
            float cc = atomicAdd(&totals[1], 0.f);
            out[0] = tt / fmaxf(cc, 1.f);
        }
    }
}

// ---------------------------------------------------------------------------
extern "C" void kernel_launch(void* const* d_in, const int* in_sizes, int n_in,
                              void* d_out, int out_size, void* d_ws, size_t ws_size,
                              hipStream_t stream) {
    (void)in_sizes; (void)n_in; (void)out_size; (void)ws_size;
    const float* z      = (const float*)d_in[0];
    const int*   labels = (const int*)d_in[1];
    float*       out    = (float*)d_out;

    char* ws = (char*)d_ws;
    float* partial_pos = (float*)(ws);                      // 2 MiB (64 x 8192 f32)
    float* partial_neg = (float*)(ws + 2097152);            // 2 MiB
    int*   hist     = (int*)  (ws + 4194304);               // 256 B
    float* totals   = (float*)(ws + 4194560);               // 8 B
    int*   done_ctr = (int*)  (ws + 4194568);               // 4 B
    unsigned char* zq = (unsigned char*)(ws + 4194816);     // 4 MiB (fp8)
    float* sq       = (float*)(ws + 4194816 + (size_t)NROW * DIM); // 32 KiB

    // no memset: prep's extra block zeroes hist/totals/done_ctr;
    // partials are written exactly once per launch.
    prep_kernel    <<<NROW / 4 + 1, 256, 0, stream>>>(z, labels, zq, sq, hist,
                                                      totals, done_ctr);
    tile_kernel    <<<NBLK, 256, 0, stream>>>(zq, sq, labels, partial_pos, partial_neg);
    rowloss_kernel <<<NROW / 256, 256, 0, stream>>>(partial_pos, partial_neg, labels,
                                                    hist, totals, done_ctr, out);
}